// Round 3
// baseline (1217.030 us; speedup 1.0000x reference)
//
#include <hip/hip_runtime.h>
#include <hip/hip_bf16.h>
#include <math.h>

#define BB 4
#define SS 2048
#define DD 512
#define HH 8
#define DEPTH 64
#define NROWS (BB*SS)
#define LN_EPS 1e-6f

typedef __attribute__((ext_vector_type(8))) short bf16x8;
typedef __attribute__((ext_vector_type(4))) float f32x4;

static __device__ inline ushort f2bf(float f) {
    __hip_bfloat16 h = __float2bfloat16(f);
    return *reinterpret_cast<ushort*>(&h);
}

// ---------------------------------------------------------------------------
// bf16-MFMA GEMM: C[M x 512] = act(A[M x 512] @ W[512 x 512] + bias)
// A, W fp32 in global; converted to bf16 during LDS staging.
// BM=BN=128, BK=32, 256 threads (4 waves), each wave owns a 64x64 sub-tile
// (4x4 fragments of 16x16), mfma_f32_16x16x32_bf16.
// act: 0 = none, 1 = leaky_relu(0.2)
// ---------------------------------------------------------------------------
#define LDP 40   // LDS row pitch in ushorts (80 B: 16B-aligned, bank-spread)

__global__ __launch_bounds__(256) void gemm_bf16_kernel(
    const float* __restrict__ A, const float* __restrict__ W,
    const float* __restrict__ bias, float* __restrict__ C, int act)
{
    __shared__ __align__(16) ushort As[128 * LDP];   // [row][k]
    __shared__ __align__(16) ushort Bs[128 * LDP];   // [col][k]  (W transposed)

    const int bm = blockIdx.y * 128;
    const int bn = blockIdx.x * 128;
    const int tid  = threadIdx.x;
    const int wave = tid >> 6;
    const int lane = tid & 63;
    const int wr = wave >> 1, wc = wave & 1;   // wave -> 64x64 sub-tile
    const int lm = lane & 15;                  // fragment row/col
    const int kg = lane >> 4;                  // k-group 0..3

    f32x4 acc[4][4] = {};

    // staging coords
    const int ar = tid >> 1;            // A: row 0..127
    const int ah = tid & 1;             // A: k-half (16 floats each)
    const int bk = tid >> 3;            // B: k 0..31
    const int bc = tid & 7;             // B: col-group

    for (int k0 = 0; k0 < DD; k0 += 32) {
        // --- stage A tile: 128 rows x 32 k (fp32 -> bf16) ---
        {
            const float* ga = &A[(size_t)(bm + ar) * DD + k0 + ah * 16];
            #pragma unroll
            for (int q = 0; q < 4; ++q) {
                float4 v = *reinterpret_cast<const float4*>(ga + q * 4);
                ushort4 sv;
                sv.x = f2bf(v.x); sv.y = f2bf(v.y);
                sv.z = f2bf(v.z); sv.w = f2bf(v.w);
                *reinterpret_cast<ushort4*>(&As[ar * LDP + ah * 16 + q * 4]) = sv;
            }
        }
        // --- stage B tile transposed: Bs[col][k] <- W[k0+k][bn+col] ---
        {
            const float* gw = &W[(size_t)(k0 + bk) * DD + bn];
            #pragma unroll
            for (int i = 0; i < 16; ++i) {
                const int col = bc + 8 * i;
                Bs[col * LDP + bk] = f2bf(gw[col]);
            }
        }
        __syncthreads();

        // --- fragments + MFMA ---
        bf16x8 af[4], bfr[4];
        #pragma unroll
        for (int m = 0; m < 4; ++m)
            af[m] = *reinterpret_cast<const bf16x8*>(
                &As[(wr * 64 + m * 16 + lm) * LDP + kg * 8]);
        #pragma unroll
        for (int n = 0; n < 4; ++n)
            bfr[n] = *reinterpret_cast<const bf16x8*>(
                &Bs[(wc * 64 + n * 16 + lm) * LDP + kg * 8]);
        #pragma unroll
        for (int m = 0; m < 4; ++m)
            #pragma unroll
            for (int n = 0; n < 4; ++n)
                acc[m][n] = __builtin_amdgcn_mfma_f32_16x16x32_bf16(
                    af[m], bfr[n], acc[m][n], 0, 0, 0);
        __syncthreads();
    }

    // --- epilogue: C/D layout col=lane&15, row=(lane>>4)*4+reg (m89-verified)
    #pragma unroll
    for (int m = 0; m < 4; ++m) {
        #pragma unroll
        for (int n = 0; n < 4; ++n) {
            const int col = bn + wc * 64 + n * 16 + lm;
            const float bv = bias ? bias[col] : 0.f;
            #pragma unroll
            for (int j = 0; j < 4; ++j) {
                const int row = bm + wr * 64 + m * 16 + kg * 4 + j;
                float v = acc[m][n][j] + bv;
                if (act == 1) v = (v > 0.f) ? v : 0.2f * v;
                C[(size_t)row * DD + col] = v;
            }
        }
    }
}

// ---------------------------------------------------------------------------
// Flash attention (fp32, unchanged baseline): per (q-tile 64, head, batch).
// qp/kp/vp are (B*S, D) with head h in cols [h*64, h*64+64).
// ctx written back into qp layout (disjoint rows x cols -> safe).
// ---------------------------------------------------------------------------
__global__ __launch_bounds__(256) void attn_kernel(
    const float* __restrict__ qp, const float* __restrict__ kp,
    const float* __restrict__ vp, const float* __restrict__ mask,
    float* __restrict__ ctx)
{
    const int qt = blockIdx.x;
    const int h  = blockIdx.y;
    const int b  = blockIdx.z;
    const int tid = threadIdx.x;
    const int tx = tid & 15, ty = tid >> 4;

    __shared__ float qs[64][DEPTH + 1];
    __shared__ float ks[64][DEPTH + 1];
    __shared__ float vs[64][DEPTH + 1];
    __shared__ float st[64][64 + 1];
    __shared__ float crow[64];

    {
        int r = tid >> 2;
        int c = (tid & 3) * 16;
        const size_t gbase = (size_t)(b * SS + qt * 64 + r) * DD + h * DEPTH + c;
        #pragma unroll
        for (int v4 = 0; v4 < 4; ++v4) {
            float4 qv = *reinterpret_cast<const float4*>(&qp[gbase + v4 * 4]);
            qs[r][c + v4 * 4 + 0] = qv.x; qs[r][c + v4 * 4 + 1] = qv.y;
            qs[r][c + v4 * 4 + 2] = qv.z; qs[r][c + v4 * 4 + 3] = qv.w;
        }
    }

    float acc[4][4] = {};
    float m_i = -1e30f, l_i = 0.f;

    for (int kt = 0; kt < SS / 64; ++kt) {
        {
            int r = tid >> 2;
            int c = (tid & 3) * 16;
            const size_t gb = (size_t)(b * SS + kt * 64 + r) * DD + h * DEPTH + c;
            #pragma unroll
            for (int v4 = 0; v4 < 4; ++v4) {
                float4 kv = *reinterpret_cast<const float4*>(&kp[gb + v4 * 4]);
                ks[r][c + v4 * 4 + 0] = kv.x; ks[r][c + v4 * 4 + 1] = kv.y;
                ks[r][c + v4 * 4 + 2] = kv.z; ks[r][c + v4 * 4 + 3] = kv.w;
                float4 vv = *reinterpret_cast<const float4*>(&vp[gb + v4 * 4]);
                vs[r][c + v4 * 4 + 0] = vv.x; vs[r][c + v4 * 4 + 1] = vv.y;
                vs[r][c + v4 * 4 + 2] = vv.z; vs[r][c + v4 * 4 + 3] = vv.w;
            }
        }
        __syncthreads();

        {
            float sacc[4][4] = {};
            #pragma unroll 8
            for (int kk = 0; kk < DEPTH; ++kk) {
                float a[4], bv[4];
                #pragma unroll
                for (int i = 0; i < 4; ++i) a[i] = qs[ty * 4 + i][kk];
                #pragma unroll
                for (int j = 0; j < 4; ++j) bv[j] = ks[tx * 4 + j][kk];
                #pragma unroll
                for (int i = 0; i < 4; ++i)
                    #pragma unroll
                    for (int j = 0; j < 4; ++j)
                        sacc[i][j] += a[i] * bv[j];
            }
            #pragma unroll
            for (int i = 0; i < 4; ++i)
                #pragma unroll
                for (int j = 0; j < 4; ++j) {
                    int kcol = kt * 64 + tx * 4 + j;
                    st[ty * 4 + i][tx * 4 + j] =
                        sacc[i][j] * 0.125f + mask[b * SS + kcol] * (-1e9f);
                }
        }
        __syncthreads();

        if (tid < 64) {
            float mt = -1e30f;
            #pragma unroll 8
            for (int c = 0; c < 64; ++c) mt = fmaxf(mt, st[tid][c]);
            float mnew = fmaxf(m_i, mt);
            float corr = __expf(m_i - mnew);
            float sum = 0.f;
            #pragma unroll 8
            for (int c = 0; c < 64; ++c) {
                float p = __expf(st[tid][c] - mnew);
                st[tid][c] = p;
                sum += p;
            }
            l_i = l_i * corr + sum;
            m_i = mnew;
            crow[tid] = corr;
        }
        __syncthreads();

        {
            #pragma unroll
            for (int i = 0; i < 4; ++i) {
                float c = crow[ty * 4 + i];
                #pragma unroll
                for (int j = 0; j < 4; ++j) acc[i][j] *= c;
            }
            #pragma unroll 8
            for (int kk = 0; kk < 64; ++kk) {
                float p[4], v[4];
                #pragma unroll
                for (int i = 0; i < 4; ++i) p[i] = st[ty * 4 + i][kk];
                #pragma unroll
                for (int j = 0; j < 4; ++j) v[j] = vs[kk][tx * 4 + j];
                #pragma unroll
                for (int i = 0; i < 4; ++i)
                    #pragma unroll
                    for (int j = 0; j < 4; ++j)
                        acc[i][j] += p[i] * v[j];
            }
        }
        __syncthreads();
    }

    if (tid < 64) crow[tid] = 1.f / l_i;
    __syncthreads();

    #pragma unroll
    for (int i = 0; i < 4; ++i) {
        const int r = ty * 4 + i;
        const size_t gr = (size_t)(b * SS + qt * 64 + r) * DD + h * DEPTH;
        const float linv = crow[r];
        #pragma unroll
        for (int j = 0; j < 4; ++j)
            ctx[gr + tx * 4 + j] = acc[i][j] * linv;
    }
}

// ---------------------------------------------------------------------------
// LayerNorm with residual: out = LN(x + res) * g + beta   (row of 512)
// ---------------------------------------------------------------------------
__global__ __launch_bounds__(256) void ln_kernel(
    const float* __restrict__ x, const float* __restrict__ res,
    const float* __restrict__ g, const float* __restrict__ bta,
    float* __restrict__ out)
{
    const int row = blockIdx.x;
    const int tid = threadIdx.x;
    const size_t base = (size_t)row * DD + tid * 2;

    float2 xv = *reinterpret_cast<const float2*>(&x[base]);
    float2 rv = *reinterpret_cast<const float2*>(&res[base]);
    float v0 = xv.x + rv.x, v1 = xv.y + rv.y;

    float s = v0 + v1;
    float ss = v0 * v0 + v1 * v1;
    #pragma unroll
    for (int off = 32; off > 0; off >>= 1) {
        s  += __shfl_down(s, off);
        ss += __shfl_down(ss, off);
    }
    __shared__ float red[2][4];
    const int wid = tid >> 6, lane = tid & 63;
    if (lane == 0) { red[0][wid] = s; red[1][wid] = ss; }
    __syncthreads();
    const float tot = red[0][0] + red[0][1] + red[0][2] + red[0][3];
    const float tsq = red[1][0] + red[1][1] + red[1][2] + red[1][3];
    const float mu = tot * (1.f / DD);
    const float var = tsq * (1.f / DD) - mu * mu;
    const float rs = rsqrtf(var + LN_EPS);

    float2 gv = *reinterpret_cast<const float2*>(&g[tid * 2]);
    float2 bv = *reinterpret_cast<const float2*>(&bta[tid * 2]);
    float2 ov;
    ov.x = (v0 - mu) * rs * gv.x + bv.x;
    ov.y = (v1 - mu) * rs * gv.y + bv.y;
    *reinterpret_cast<float2*>(&out[base]) = ov;
}

// ---------------------------------------------------------------------------
extern "C" void kernel_launch(void* const* d_in, const int* in_sizes, int n_in,
                              void* d_out, int out_size, void* d_ws, size_t ws_size,
                              hipStream_t stream)
{
    (void)in_sizes; (void)n_in; (void)out_size; (void)ws_size;
    const float* q     = (const float*)d_in[0];
    const float* k     = (const float*)d_in[1];
    const float* mask  = (const float*)d_in[2];
    const float* wq    = (const float*)d_in[3];
    const float* wk    = (const float*)d_in[4];
    const float* wv    = (const float*)d_in[5];
    const float* wo    = (const float*)d_in[6];
    const float* w1    = (const float*)d_in[7];
    const float* b1    = (const float*)d_in[8];
    const float* w2    = (const float*)d_in[9];
    const float* b2    = (const float*)d_in[10];
    const float* g1    = (const float*)d_in[11];
    const float* beta1 = (const float*)d_in[12];
    const float* g2    = (const float*)d_in[13];
    const float* beta2 = (const float*)d_in[14];
    float* out = (float*)d_out;

    float* ws = (float*)d_ws;
    const size_t BUF = (size_t)NROWS * DD;   // 4 Mi elems = 16 MB
    float* qp = ws;            // q-proj, then ctx (in place)
    float* kp = ws + BUF;      // k-proj, then FFN hidden
    float* vp = ws + 2 * BUF;  // v-proj, then attn_out / out1

    const dim3 blk(256);
    const dim3 ggrid(DD / 128, NROWS / 128);     // 4 x 64 = 256 blocks

    // projections (bf16 MFMA)
    gemm_bf16_kernel<<<ggrid, blk, 0, stream>>>(q, wq, nullptr, qp, 0);
    gemm_bf16_kernel<<<ggrid, blk, 0, stream>>>(k, wk, nullptr, kp, 0);
    gemm_bf16_kernel<<<ggrid, blk, 0, stream>>>(k, wv, nullptr, vp, 0);

    // attention (fp32; ctx written in-place into qp)
    attn_kernel<<<dim3(SS / 64, HH, BB), blk, 0, stream>>>(qp, kp, vp, mask, qp);

    // attn_out = ctx @ wo -> vp ; out1 = LN(q + attn_out) -> vp (in place)
    gemm_bf16_kernel<<<ggrid, blk, 0, stream>>>(qp, wo, nullptr, vp, 0);
    ln_kernel<<<dim3(NROWS), blk, 0, stream>>>(vp, q, g1, beta1, vp);

    // FFN
    gemm_bf16_kernel<<<ggrid, blk, 0, stream>>>(vp, w1, b1, kp, 1);   // hidden
    gemm_bf16_kernel<<<ggrid, blk, 0, stream>>>(kp, w2, b2, out, 0);  // ffn_out
    ln_kernel<<<dim3(NROWS), blk, 0, stream>>>(out, vp, g2, beta2, out);
}

// Round 5
// 452.423 us; speedup vs baseline: 2.6900x; 2.6900x over previous
//
#include <hip/hip_runtime.h>
#include <hip/hip_bf16.h>
#include <math.h>

#define BB 4
#define SS 2048
#define DD 512
#define HH 8
#define DEPTH 64
#define NROWS (BB*SS)
#define LN_EPS 1e-6f

typedef __attribute__((ext_vector_type(8))) short bf16x8;
typedef __attribute__((ext_vector_type(4))) float f32x4;

static __device__ inline ushort f2bf(float f) {
    __hip_bfloat16 h = __float2bfloat16(f);
    return *reinterpret_cast<ushort*>(&h);
}

// ---------------------------------------------------------------------------
// bf16-MFMA GEMM (unchanged from passing round)
// C[M x 512] = act(A[M x 512] @ W[512 x 512] + bias)
// BM=BN=128, BK=32, 256 threads (4 waves), wave owns 64x64, 16x16x32 MFMA.
// ---------------------------------------------------------------------------
#define LDP 40   // LDS row pitch in ushorts (80 B)

__global__ __launch_bounds__(256) void gemm_bf16_kernel(
    const float* __restrict__ A, const float* __restrict__ W,
    const float* __restrict__ bias, float* __restrict__ C, int act)
{
    __shared__ __align__(16) ushort As[128 * LDP];   // [row][k]
    __shared__ __align__(16) ushort Bs[128 * LDP];   // [col][k]  (W transposed)

    const int bm = blockIdx.y * 128;
    const int bn = blockIdx.x * 128;
    const int tid  = threadIdx.x;
    const int wave = tid >> 6;
    const int lane = tid & 63;
    const int wr = wave >> 1, wc = wave & 1;
    const int lm = lane & 15;
    const int kg = lane >> 4;

    f32x4 acc[4][4] = {};

    const int ar = tid >> 1;
    const int ah = tid & 1;
    const int bk = tid >> 3;
    const int bc = tid & 7;

    for (int k0 = 0; k0 < DD; k0 += 32) {
        {
            const float* ga = &A[(size_t)(bm + ar) * DD + k0 + ah * 16];
            #pragma unroll
            for (int q = 0; q < 4; ++q) {
                float4 v = *reinterpret_cast<const float4*>(ga + q * 4);
                ushort4 sv;
                sv.x = f2bf(v.x); sv.y = f2bf(v.y);
                sv.z = f2bf(v.z); sv.w = f2bf(v.w);
                *reinterpret_cast<ushort4*>(&As[ar * LDP + ah * 16 + q * 4]) = sv;
            }
        }
        {
            const float* gw = &W[(size_t)(k0 + bk) * DD + bn];
            #pragma unroll
            for (int i = 0; i < 16; ++i) {
                const int col = bc + 8 * i;
                Bs[col * LDP + bk] = f2bf(gw[col]);
            }
        }
        __syncthreads();

        bf16x8 af[4], bfr[4];
        #pragma unroll
        for (int m = 0; m < 4; ++m)
            af[m] = *reinterpret_cast<const bf16x8*>(
                &As[(wr * 64 + m * 16 + lm) * LDP + kg * 8]);
        #pragma unroll
        for (int n = 0; n < 4; ++n)
            bfr[n] = *reinterpret_cast<const bf16x8*>(
                &Bs[(wc * 64 + n * 16 + lm) * LDP + kg * 8]);
        #pragma unroll
        for (int m = 0; m < 4; ++m)
            #pragma unroll
            for (int n = 0; n < 4; ++n)
                acc[m][n] = __builtin_amdgcn_mfma_f32_16x16x32_bf16(
                    af[m], bfr[n], acc[m][n], 0, 0, 0);
        __syncthreads();
    }

    #pragma unroll
    for (int m = 0; m < 4; ++m) {
        #pragma unroll
        for (int n = 0; n < 4; ++n) {
            const int col = bn + wc * 64 + n * 16 + lm;
            const float bv = bias ? bias[col] : 0.f;
            #pragma unroll
            for (int j = 0; j < 4; ++j) {
                const int row = bm + wr * 64 + m * 16 + kg * 4 + j;
                float v = acc[m][n][j] + bv;
                if (act == 1) v = (v > 0.f) ? v : 0.2f * v;
                C[(size_t)row * DD + col] = v;
            }
        }
    }
}

// ---------------------------------------------------------------------------
// bf16-MFMA flash attention. Block = (64-row q-tile, head, batch), 4 waves.
// qp/kp/vp: (B*S, D), head h in cols [h*64, h*64+64). ctx -> qp in place.
//
// QK^T: Q,K staged row-major bf16 [row][d] (K rows ARE the B^T layout).
// PV:   V staged transposed vsT[d][k] with chunk-XOR swizzle
//       e(d,k) = ((k>>3) ^ ((d>>3)&7))*8 + (k&7)   (self-inverse in chunk idx)
//       -> fragment reads stay 8-contiguous & 16B-aligned; scatter-write
//       conflicts drop from 8-way to ~2-way.
// Softmax: S fp32 in LDS, 4 threads/row, shfl_xor(1,2) reductions, online m/l.
// ---------------------------------------------------------------------------
#define AP 72   // bf16 tile pitch (ushorts) = 144 B = 9*16
#define SP 68   // st pitch (floats) = 272 B = 17*16

__global__ __launch_bounds__(256) void attn_mfma_kernel(
    const float* __restrict__ qp, const float* __restrict__ kp,
    const float* __restrict__ vp, const float* __restrict__ mask,
    float* __restrict__ ctx)
{
    __shared__ __align__(16) ushort qs[64 * AP];
    __shared__ __align__(16) ushort ksh[64 * AP];
    __shared__ __align__(16) ushort vsT[64 * AP];
    __shared__ __align__(16) ushort pt[64 * AP];
    __shared__ __align__(16) float  st[64 * SP];
    __shared__ float crow[64];
    __shared__ float linv[64];

    const int qt = blockIdx.x, h = blockIdx.y, b = blockIdx.z;
    const int tid = threadIdx.x;
    const int wave = tid >> 6, lane = tid & 63;
    const int lm = lane & 15, kg = lane >> 4;
    const int r4 = tid >> 2;   // staging/softmax row 0..63
    const int c4 = tid & 3;    // 16-col group

    // ---- stage Q tile (fp32 -> bf16), reused for all kt ----
    {
        const float* gq = &qp[(size_t)(b*SS + qt*64 + r4)*DD + h*DEPTH + c4*16];
        ushort tmp[16];
        #pragma unroll
        for (int q = 0; q < 4; ++q) {
            float4 v = *reinterpret_cast<const float4*>(gq + q*4);
            tmp[q*4+0] = f2bf(v.x); tmp[q*4+1] = f2bf(v.y);
            tmp[q*4+2] = f2bf(v.z); tmp[q*4+3] = f2bf(v.w);
        }
        *reinterpret_cast<bf16x8*>(&qs[r4*AP + c4*16])     = *reinterpret_cast<bf16x8*>(&tmp[0]);
        *reinterpret_cast<bf16x8*>(&qs[r4*AP + c4*16 + 8]) = *reinterpret_cast<bf16x8*>(&tmp[8]);
    }

    f32x4 acc[4] = {};            // wave's d-strip (cols wave*16..+15), 4 m-frags
    float m_i = -1e30f, l_i = 0.f;

    for (int kt = 0; kt < SS/64; ++kt) {
        __syncthreads();          // prev-iter readers of ksh/vsT/pt done

        // ---- stage K rows + V transposed-swizzled ----
        {
            const size_t gb = (size_t)(b*SS + kt*64 + r4)*DD + h*DEPTH + c4*16;
            ushort tmp[16];
            #pragma unroll
            for (int q = 0; q < 4; ++q) {
                float4 v = *reinterpret_cast<const float4*>(&kp[gb + q*4]);
                tmp[q*4+0] = f2bf(v.x); tmp[q*4+1] = f2bf(v.y);
                tmp[q*4+2] = f2bf(v.z); tmp[q*4+3] = f2bf(v.w);
            }
            *reinterpret_cast<bf16x8*>(&ksh[r4*AP + c4*16])     = *reinterpret_cast<bf16x8*>(&tmp[0]);
            *reinterpret_cast<bf16x8*>(&ksh[r4*AP + c4*16 + 8]) = *reinterpret_cast<bf16x8*>(&tmp[8]);

            float vv[16];
            #pragma unroll
            for (int q = 0; q < 4; ++q) {
                float4 v = *reinterpret_cast<const float4*>(&vp[gb + q*4]);
                vv[q*4+0] = v.x; vv[q*4+1] = v.y; vv[q*4+2] = v.z; vv[q*4+3] = v.w;
            }
            #pragma unroll
            for (int i = 0; i < 16; ++i) {
                const int dloc = c4*16 + i;               // V column (output d)
                const int e = (((r4>>3) ^ ((dloc>>3)&7)) << 3) | (r4 & 7);
                vsT[dloc*AP + e] = f2bf(vv[i]);
            }
        }
        __syncthreads();

        // ---- QK^T: wave owns S cols wave*16..+15 ----
        {
            f32x4 s[4] = {};
            #pragma unroll
            for (int ks_ = 0; ks_ < 2; ++ks_) {
                bf16x8 bfrag = *reinterpret_cast<const bf16x8*>(
                    &ksh[(wave*16 + lm)*AP + ks_*32 + kg*8]);
                #pragma unroll
                for (int m = 0; m < 4; ++m) {
                    bf16x8 afrag = *reinterpret_cast<const bf16x8*>(
                        &qs[(m*16 + lm)*AP + ks_*32 + kg*8]);
                    s[m] = __builtin_amdgcn_mfma_f32_16x16x32_bf16(
                        afrag, bfrag, s[m], 0, 0, 0);
                }
            }
            const int kcol = kt*64 + wave*16 + lm;
            const float mval = mask[b*SS + kcol] * (-1e9f);
            #pragma unroll
            for (int m = 0; m < 4; ++m)
                #pragma unroll
                for (int j = 0; j < 4; ++j)
                    st[(m*16 + kg*4 + j)*SP + wave*16 + lm] = s[m][j]*0.125f + mval;
        }
        __syncthreads();

        // ---- online softmax: 4 threads per row, 16 cols each ----
        {
            float p[16];
            #pragma unroll
            for (int q = 0; q < 4; ++q) {
                float4 t = *reinterpret_cast<const float4*>(&st[r4*SP + c4*16 + q*4]);
                p[q*4+0] = t.x; p[q*4+1] = t.y; p[q*4+2] = t.z; p[q*4+3] = t.w;
            }
            float mt = p[0];
            #pragma unroll
            for (int i = 1; i < 16; ++i) mt = fmaxf(mt, p[i]);
            mt = fmaxf(mt, __shfl_xor(mt, 1));
            mt = fmaxf(mt, __shfl_xor(mt, 2));
            const float mnew = fmaxf(m_i, mt);
            const float corr = __expf(m_i - mnew);
            float sum = 0.f;
            ushort tmp[16];
            #pragma unroll
            for (int i = 0; i < 16; ++i) {
                float e = __expf(p[i] - mnew);
                sum += e;
                tmp[i] = f2bf(e);
            }
            sum += __shfl_xor(sum, 1);
            sum += __shfl_xor(sum, 2);
            l_i = l_i * corr + sum;
            m_i = mnew;
            *reinterpret_cast<bf16x8*>(&pt[r4*AP + c4*16])     = *reinterpret_cast<bf16x8*>(&tmp[0]);
            *reinterpret_cast<bf16x8*>(&pt[r4*AP + c4*16 + 8]) = *reinterpret_cast<bf16x8*>(&tmp[8]);
            if (c4 == 0) crow[r4] = corr;
        }
        __syncthreads();

        // ---- rescale + PV: wave's d-strip ----
        {
            #pragma unroll
            for (int m = 0; m < 4; ++m)
                #pragma unroll
                for (int j = 0; j < 4; ++j)
                    acc[m][j] *= crow[m*16 + kg*4 + j];

            const int dloc = wave*16 + lm;
            const int zz = (dloc >> 3) & 7;
            #pragma unroll
            for (int ks_ = 0; ks_ < 2; ++ks_) {
                const int chunk = (ks_*4 + kg) ^ zz;
                bf16x8 bfrag = *reinterpret_cast<const bf16x8*>(
                    &vsT[dloc*AP + chunk*8]);
                #pragma unroll
                for (int m = 0; m < 4; ++m) {
                    bf16x8 afrag = *reinterpret_cast<const bf16x8*>(
                        &pt[(m*16 + lm)*AP + ks_*32 + kg*8]);
                    acc[m] = __builtin_amdgcn_mfma_f32_16x16x32_bf16(
                        afrag, bfrag, acc[m], 0, 0, 0);
                }
            }
        }
    }

    if (c4 == 0) linv[r4] = 1.f / l_i;
    __syncthreads();

    {
        const int dloc = wave*16 + lm;
        #pragma unroll
        for (int m = 0; m < 4; ++m)
            #pragma unroll
            for (int j = 0; j < 4; ++j) {
                const int row = m*16 + kg*4 + j;
                ctx[(size_t)(b*SS + qt*64 + row)*DD + h*DEPTH + dloc] =
                    acc[m][j] * linv[row];
            }
    }
}

// ---------------------------------------------------------------------------
// LayerNorm with residual (unchanged)
// ---------------------------------------------------------------------------
__global__ __launch_bounds__(256) void ln_kernel(
    const float* __restrict__ x, const float* __restrict__ res,
    const float* __restrict__ g, const float* __restrict__ bta,
    float* __restrict__ out)
{
    const int row = blockIdx.x;
    const int tid = threadIdx.x;
    const size_t base = (size_t)row * DD + tid * 2;

    float2 xv = *reinterpret_cast<const float2*>(&x[base]);
    float2 rv = *reinterpret_cast<const float2*>(&res[base]);
    float v0 = xv.x + rv.x, v1 = xv.y + rv.y;

    float s = v0 + v1;
    float ss = v0 * v0 + v1 * v1;
    #pragma unroll
    for (int off = 32; off > 0; off >>= 1) {
        s  += __shfl_down(s, off);
        ss += __shfl_down(ss, off);
    }
    __shared__ float red[2][4];
    const int wid = tid >> 6, lane = tid & 63;
    if (lane == 0) { red[0][wid] = s; red[1][wid] = ss; }
    __syncthreads();
    const float tot = red[0][0] + red[0][1] + red[0][2] + red[0][3];
    const float tsq = red[1][0] + red[1][1] + red[1][2] + red[1][3];
    const float mu = tot * (1.f / DD);
    const float var = tsq * (1.f / DD) - mu * mu;
    const float rs = rsqrtf(var + LN_EPS);

    float2 gv = *reinterpret_cast<const float2*>(&g[tid * 2]);
    float2 bv = *reinterpret_cast<const float2*>(&bta[tid * 2]);
    float2 ov;
    ov.x = (v0 - mu) * rs * gv.x + bv.x;
    ov.y = (v1 - mu) * rs * gv.y + bv.y;
    *reinterpret_cast<float2*>(&out[base]) = ov;
}

// ---------------------------------------------------------------------------
extern "C" void kernel_launch(void* const* d_in, const int* in_sizes, int n_in,
                              void* d_out, int out_size, void* d_ws, size_t ws_size,
                              hipStream_t stream)
{
    (void)in_sizes; (void)n_in; (void)out_size; (void)ws_size;
    const float* q     = (const float*)d_in[0];
    const float* k     = (const float*)d_in[1];
    const float* mask  = (const float*)d_in[2];
    const float* wq    = (const float*)d_in[3];
    const float* wk    = (const float*)d_in[4];
    const float* wv    = (const float*)d_in[5];
    const float* wo    = (const float*)d_in[6];
    const float* w1    = (const float*)d_in[7];
    const float* b1    = (const float*)d_in[8];
    const float* w2    = (const float*)d_in[9];
    const float* b2    = (const float*)d_in[10];
    const float* g1    = (const float*)d_in[11];
    const float* beta1 = (const float*)d_in[12];
    const float* g2    = (const float*)d_in[13];
    const float* beta2 = (const float*)d_in[14];
    float* out = (float*)d_out;

    float* ws = (float*)d_ws;
    const size_t BUF = (size_t)NROWS * DD;   // 16 MB
    float* qp = ws;            // q-proj, then ctx (in place)
    float* kp = ws + BUF;      // k-proj, then FFN hidden
    float* vp = ws + 2 * BUF;  // v-proj, then attn_out / out1

    const dim3 blk(256);
    const dim3 ggrid(DD / 128, NROWS / 128);     // 4 x 64 = 256 blocks

    gemm_bf16_kernel<<<ggrid, blk, 0, stream>>>(q, wq, nullptr, qp, 0);
    gemm_bf16_kernel<<<ggrid, blk, 0, stream>>>(k, wk, nullptr, kp, 0);
    gemm_bf16_kernel<<<ggrid, blk, 0, stream>>>(k, wv, nullptr, vp, 0);

    attn_mfma_kernel<<<dim3(SS / 64, HH, BB), blk, 0, stream>>>(qp, kp, vp, mask, qp);

    gemm_bf16_kernel<<<ggrid, blk, 0, stream>>>(qp, wo, nullptr, vp, 0);
    ln_kernel<<<dim3(NROWS), blk, 0, stream>>>(vp, q, g1, beta1, vp);

    gemm_bf16_kernel<<<ggrid, blk, 0, stream>>>(vp, w1, b1, kp, 1);
    gemm_bf16_kernel<<<ggrid, blk, 0, stream>>>(kp, w2, b2, out, 0);
    ln_kernel<<<dim3(NROWS), blk, 0, stream>>>(out, vp, g2, beta2, out);
}

// Round 8
// 388.999 us; speedup vs baseline: 3.1286x; 1.1630x over previous
//
#include <hip/hip_runtime.h>
#include <hip/hip_bf16.h>
#include <math.h>

#define BB 4
#define SS 2048
#define DD 512
#define HH 8
#define DEPTH 64
#define NROWS (BB*SS)
#define LN_EPS 1e-6f

typedef __attribute__((ext_vector_type(8))) short bf16x8;
typedef __attribute__((ext_vector_type(4))) float f32x4;

static __device__ inline ushort f2bf(float f) {
    __hip_bfloat16 h = __float2bfloat16(f);
    return *reinterpret_cast<ushort*>(&h);
}
static __device__ inline float bf2f(ushort u) {
    __hip_bfloat16 h = *reinterpret_cast<__hip_bfloat16*>(&u);
    return __bfloat162float(h);
}

// ---------------------------------------------------------------------------
// Weight pre-transpose: W[512][512] fp32 -> WT[n][k] bf16, all 6 weights.
// grid (8,8,6): 64x64 tile per block, 256 threads.
// ---------------------------------------------------------------------------
__global__ __launch_bounds__(256) void wtrans_kernel(
    const float* __restrict__ w0, const float* __restrict__ w1,
    const float* __restrict__ w2, const float* __restrict__ w3,
    const float* __restrict__ w4, const float* __restrict__ w5,
    ushort* __restrict__ wt)
{
    const float* W;
    switch (blockIdx.z) {
        case 0: W = w0; break; case 1: W = w1; break; case 2: W = w2; break;
        case 3: W = w3; break; case 4: W = w4; break; default: W = w5; break;
    }
    ushort* WT = wt + (size_t)blockIdx.z * DD * DD;

    __shared__ ushort t[64][72];   // t[k_local][n_local]
    const int kt = blockIdx.x * 64, nt = blockIdx.y * 64;
    const int tid = threadIdx.x;
    const int r = tid >> 2, cg = tid & 3;

    #pragma unroll
    for (int q = 0; q < 4; ++q) {
        float4 v = *reinterpret_cast<const float4*>(
            &W[(size_t)(kt + r) * DD + nt + cg * 16 + q * 4]);
        t[r][cg * 16 + q * 4 + 0] = f2bf(v.x);
        t[r][cg * 16 + q * 4 + 1] = f2bf(v.y);
        t[r][cg * 16 + q * 4 + 2] = f2bf(v.z);
        t[r][cg * 16 + q * 4 + 3] = f2bf(v.w);
    }
    __syncthreads();

    ushort tmp[16];
    #pragma unroll
    for (int i = 0; i < 16; ++i) tmp[i] = t[cg * 16 + i][r];
    *reinterpret_cast<bf16x8*>(&WT[(size_t)(nt + r) * DD + kt + cg * 16]) =
        *reinterpret_cast<bf16x8*>(&tmp[0]);
    *reinterpret_cast<bf16x8*>(&WT[(size_t)(nt + r) * DD + kt + cg * 16 + 8]) =
        *reinterpret_cast<bf16x8*>(&tmp[8]);
}

// ---------------------------------------------------------------------------
// bf16-MFMA GEMM. C[M x 512] = act(A[M x 512] @ W[512 x 512] + bias)
// A: fp32 (converted in staging) or bf16 (vector copy). W from bf16 WT[n][k].
// C: fp32 or bf16. BM=BN=128, BK=32, 4 waves, wave owns 64x64.
// Fragment paths identical to round-5 passing kernel.
// ---------------------------------------------------------------------------
#define LDP 40   // LDS row pitch in ushorts (80 B)

template<typename AT, typename CT, int ACT>
__global__ __launch_bounds__(256) void gemm2_kernel(
    const AT* __restrict__ A, const ushort* __restrict__ WT,
    const float* __restrict__ bias, CT* __restrict__ C)
{
    __shared__ __align__(16) ushort As[128 * LDP];   // [row][k]
    __shared__ __align__(16) ushort Bs[128 * LDP];   // [col][k]

    const int bm = blockIdx.y * 128;
    const int bn = blockIdx.x * 128;
    const int tid  = threadIdx.x;
    const int wave = tid >> 6;
    const int lane = tid & 63;
    const int wr = wave >> 1, wc = wave & 1;
    const int lm = lane & 15;
    const int kg = lane >> 4;

    f32x4 acc[4][4] = {};

    const int sr = tid >> 1;      // staging row/col 0..127
    const int sh = tid & 1;       // k-half (16 elements)

    for (int k0 = 0; k0 < DD; k0 += 32) {
        // --- stage A tile: 128 rows x 32 k ---
        if constexpr (sizeof(AT) == 4) {
            const float* ga = (const float*)&A[(size_t)(bm + sr) * DD + k0 + sh * 16];
            ushort tmp[16];
            #pragma unroll
            for (int q = 0; q < 4; ++q) {
                float4 v = *reinterpret_cast<const float4*>(ga + q * 4);
                tmp[q*4+0] = f2bf(v.x); tmp[q*4+1] = f2bf(v.y);
                tmp[q*4+2] = f2bf(v.z); tmp[q*4+3] = f2bf(v.w);
            }
            *reinterpret_cast<bf16x8*>(&As[sr * LDP + sh * 16])     = *reinterpret_cast<bf16x8*>(&tmp[0]);
            *reinterpret_cast<bf16x8*>(&As[sr * LDP + sh * 16 + 8]) = *reinterpret_cast<bf16x8*>(&tmp[8]);
        } else {
            const ushort* ga = (const ushort*)&A[(size_t)(bm + sr) * DD + k0 + sh * 16];
            *reinterpret_cast<bf16x8*>(&As[sr * LDP + sh * 16]) =
                *reinterpret_cast<const bf16x8*>(ga);
            *reinterpret_cast<bf16x8*>(&As[sr * LDP + sh * 16 + 8]) =
                *reinterpret_cast<const bf16x8*>(ga + 8);
        }
        // --- stage B tile: Bs[col][k] <- WT[bn+col][k0..k0+31] (vector) ---
        {
            const ushort* gw = &WT[(size_t)(bn + sr) * DD + k0 + sh * 16];
            *reinterpret_cast<bf16x8*>(&Bs[sr * LDP + sh * 16]) =
                *reinterpret_cast<const bf16x8*>(gw);
            *reinterpret_cast<bf16x8*>(&Bs[sr * LDP + sh * 16 + 8]) =
                *reinterpret_cast<const bf16x8*>(gw + 8);
        }
        __syncthreads();

        bf16x8 af[4], bfr[4];
        #pragma unroll
        for (int m = 0; m < 4; ++m)
            af[m] = *reinterpret_cast<const bf16x8*>(
                &As[(wr * 64 + m * 16 + lm) * LDP + kg * 8]);
        #pragma unroll
        for (int n = 0; n < 4; ++n)
            bfr[n] = *reinterpret_cast<const bf16x8*>(
                &Bs[(wc * 64 + n * 16 + lm) * LDP + kg * 8]);
        #pragma unroll
        for (int m = 0; m < 4; ++m)
            #pragma unroll
            for (int n = 0; n < 4; ++n)
                acc[m][n] = __builtin_amdgcn_mfma_f32_16x16x32_bf16(
                    af[m], bfr[n], acc[m][n], 0, 0, 0);
        __syncthreads();
    }

    // --- epilogue: C/D layout col=lane&15, row=(lane>>4)*4+reg (verified) ---
    #pragma unroll
    for (int m = 0; m < 4; ++m) {
        #pragma unroll
        for (int n = 0; n < 4; ++n) {
            const int col = bn + wc * 64 + n * 16 + lm;
            const float bv = bias ? bias[col] : 0.f;
            #pragma unroll
            for (int j = 0; j < 4; ++j) {
                const int row = bm + wr * 64 + m * 16 + kg * 4 + j;
                float v = acc[m][n][j] + bv;
                if (ACT == 1) v = (v > 0.f) ? v : 0.2f * v;
                if constexpr (sizeof(CT) == 4)
                    C[(size_t)row * DD + col] = v;
                else
                    C[(size_t)row * DD + col] = f2bf(v);
            }
        }
    }
}

// ---------------------------------------------------------------------------
// bf16-MFMA flash attention (round-5 structure; inputs/outputs now bf16).
// Block = (64-row q-tile, head, batch), 4 waves. ctx -> qp in place.
// ---------------------------------------------------------------------------
#define AP 72   // bf16 tile pitch (ushorts) = 144 B
#define SP 68   // st pitch (floats) = 272 B

__global__ __launch_bounds__(256) void attn_mfma_kernel(
    const ushort* __restrict__ qp, const ushort* __restrict__ kp,
    const ushort* __restrict__ vp, const float* __restrict__ mask,
    ushort* __restrict__ ctx)
{
    __shared__ __align__(16) ushort qs[64 * AP];
    __shared__ __align__(16) ushort ksh[64 * AP];
    __shared__ __align__(16) ushort vsT[64 * AP];
    __shared__ __align__(16) ushort pt[64 * AP];
    __shared__ __align__(16) float  st[64 * SP];
    __shared__ float crow[64];
    __shared__ float linv[64];

    const int qt = blockIdx.x, h = blockIdx.y, b = blockIdx.z;
    const int tid = threadIdx.x;
    const int wave = tid >> 6, lane = tid & 63;
    const int lm = lane & 15, kg = lane >> 4;
    const int r4 = tid >> 2;
    const int c4 = tid & 3;

    // ---- stage Q tile (bf16 vector copy), reused for all kt ----
    {
        const ushort* gq = &qp[(size_t)(b*SS + qt*64 + r4)*DD + h*DEPTH + c4*16];
        *reinterpret_cast<bf16x8*>(&qs[r4*AP + c4*16])     = *reinterpret_cast<const bf16x8*>(gq);
        *reinterpret_cast<bf16x8*>(&qs[r4*AP + c4*16 + 8]) = *reinterpret_cast<const bf16x8*>(gq + 8);
    }

    f32x4 acc[4] = {};
    float m_i = -1e30f, l_i = 0.f;

    for (int kt = 0; kt < SS/64; ++kt) {
        __syncthreads();

        // ---- stage K rows + V transposed-swizzled ----
        {
            const size_t gb = (size_t)(b*SS + kt*64 + r4)*DD + h*DEPTH + c4*16;
            *reinterpret_cast<bf16x8*>(&ksh[r4*AP + c4*16])     = *reinterpret_cast<const bf16x8*>(&kp[gb]);
            *reinterpret_cast<bf16x8*>(&ksh[r4*AP + c4*16 + 8]) = *reinterpret_cast<const bf16x8*>(&kp[gb + 8]);

            ushort tv[16];
            *reinterpret_cast<bf16x8*>(&tv[0]) = *reinterpret_cast<const bf16x8*>(&vp[gb]);
            *reinterpret_cast<bf16x8*>(&tv[8]) = *reinterpret_cast<const bf16x8*>(&vp[gb + 8]);
            #pragma unroll
            for (int i = 0; i < 16; ++i) {
                const int dloc = c4*16 + i;
                const int e = (((r4>>3) ^ ((dloc>>3)&7)) << 3) | (r4 & 7);
                vsT[dloc*AP + e] = tv[i];
            }
        }
        __syncthreads();

        // ---- QK^T: wave owns S cols wave*16..+15 ----
        {
            f32x4 s[4] = {};
            #pragma unroll
            for (int ks_ = 0; ks_ < 2; ++ks_) {
                bf16x8 bfrag = *reinterpret_cast<const bf16x8*>(
                    &ksh[(wave*16 + lm)*AP + ks_*32 + kg*8]);
                #pragma unroll
                for (int m = 0; m < 4; ++m) {
                    bf16x8 afrag = *reinterpret_cast<const bf16x8*>(
                        &qs[(m*16 + lm)*AP + ks_*32 + kg*8]);
                    s[m] = __builtin_amdgcn_mfma_f32_16x16x32_bf16(
                        afrag, bfrag, s[m], 0, 0, 0);
                }
            }
            const int kcol = kt*64 + wave*16 + lm;
            const float mval = mask[b*SS + kcol] * (-1e9f);
            #pragma unroll
            for (int m = 0; m < 4; ++m)
                #pragma unroll
                for (int j = 0; j < 4; ++j)
                    st[(m*16 + kg*4 + j)*SP + wave*16 + lm] = s[m][j]*0.125f + mval;
        }
        __syncthreads();

        // ---- online softmax: 4 threads per row ----
        {
            float p[16];
            #pragma unroll
            for (int q = 0; q < 4; ++q) {
                float4 t = *reinterpret_cast<const float4*>(&st[r4*SP + c4*16 + q*4]);
                p[q*4+0] = t.x; p[q*4+1] = t.y; p[q*4+2] = t.z; p[q*4+3] = t.w;
            }
            float mt = p[0];
            #pragma unroll
            for (int i = 1; i < 16; ++i) mt = fmaxf(mt, p[i]);
            mt = fmaxf(mt, __shfl_xor(mt, 1));
            mt = fmaxf(mt, __shfl_xor(mt, 2));
            const float mnew = fmaxf(m_i, mt);
            const float corr = __expf(m_i - mnew);
            float sum = 0.f;
            ushort tmp[16];
            #pragma unroll
            for (int i = 0; i < 16; ++i) {
                float e = __expf(p[i] - mnew);
                sum += e;
                tmp[i] = f2bf(e);
            }
            sum += __shfl_xor(sum, 1);
            sum += __shfl_xor(sum, 2);
            l_i = l_i * corr + sum;
            m_i = mnew;
            *reinterpret_cast<bf16x8*>(&pt[r4*AP + c4*16])     = *reinterpret_cast<bf16x8*>(&tmp[0]);
            *reinterpret_cast<bf16x8*>(&pt[r4*AP + c4*16 + 8]) = *reinterpret_cast<bf16x8*>(&tmp[8]);
            if (c4 == 0) crow[r4] = corr;
        }
        __syncthreads();

        // ---- rescale + PV ----
        {
            #pragma unroll
            for (int m = 0; m < 4; ++m)
                #pragma unroll
                for (int j = 0; j < 4; ++j)
                    acc[m][j] *= crow[m*16 + kg*4 + j];

            const int dloc = wave*16 + lm;
            const int zz = (dloc >> 3) & 7;
            #pragma unroll
            for (int ks_ = 0; ks_ < 2; ++ks_) {
                const int chunk = (ks_*4 + kg) ^ zz;
                bf16x8 bfrag = *reinterpret_cast<const bf16x8*>(
                    &vsT[dloc*AP + chunk*8]);
                #pragma unroll
                for (int m = 0; m < 4; ++m) {
                    bf16x8 afrag = *reinterpret_cast<const bf16x8*>(
                        &pt[(m*16 + lm)*AP + ks_*32 + kg*8]);
                    acc[m] = __builtin_amdgcn_mfma_f32_16x16x32_bf16(
                        afrag, bfrag, acc[m], 0, 0, 0);
                }
            }
        }
    }

    if (c4 == 0) linv[r4] = 1.f / l_i;
    __syncthreads();

    {
        const int dloc = wave*16 + lm;
        #pragma unroll
        for (int m = 0; m < 4; ++m)
            #pragma unroll
            for (int j = 0; j < 4; ++j) {
                const int row = m*16 + kg*4 + j;
                ctx[(size_t)(b*SS + qt*64 + row)*DD + h*DEPTH + dloc] =
                    f2bf(acc[m][j] * linv[row]);
            }
    }
}

// ---------------------------------------------------------------------------
// LayerNorm with residual: out = LN(x + res)*g + beta (fp32), optional bf16 copy
// ---------------------------------------------------------------------------
__global__ __launch_bounds__(256) void ln_kernel(
    const float* __restrict__ x, const float* __restrict__ res,
    const float* __restrict__ g, const float* __restrict__ bta,
    float* __restrict__ out, ushort* __restrict__ outb)
{
    const int row = blockIdx.x;
    const int tid = threadIdx.x;
    const size_t base = (size_t)row * DD + tid * 2;

    float2 xv = *reinterpret_cast<const float2*>(&x[base]);
    float2 rv = *reinterpret_cast<const float2*>(&res[base]);
    float v0 = xv.x + rv.x, v1 = xv.y + rv.y;

    float s = v0 + v1;
    float ss = v0 * v0 + v1 * v1;
    #pragma unroll
    for (int off = 32; off > 0; off >>= 1) {
        s  += __shfl_down(s, off);
        ss += __shfl_down(ss, off);
    }
    __shared__ float red[2][4];
    const int wid = tid >> 6, lane = tid & 63;
    if (lane == 0) { red[0][wid] = s; red[1][wid] = ss; }
    __syncthreads();
    const float tot = red[0][0] + red[0][1] + red[0][2] + red[0][3];
    const float tsq = red[1][0] + red[1][1] + red[1][2] + red[1][3];
    const float mu = tot * (1.f / DD);
    const float var = tsq * (1.f / DD) - mu * mu;
    const float rs = rsqrtf(var + LN_EPS);

    float2 gv = *reinterpret_cast<const float2*>(&g[tid * 2]);
    float2 bv = *reinterpret_cast<const float2*>(&bta[tid * 2]);
    float2 ov;
    ov.x = (v0 - mu) * rs * gv.x + bv.x;
    ov.y = (v1 - mu) * rs * gv.y + bv.y;
    *reinterpret_cast<float2*>(&out[base]) = ov;
    if (outb) {
        ushort2 ob; ob.x = f2bf(ov.x); ob.y = f2bf(ov.y);
        *reinterpret_cast<ushort2*>(&outb[base]) = ob;
    }
}

// ---------------------------------------------------------------------------
extern "C" void kernel_launch(void* const* d_in, const int* in_sizes, int n_in,
                              void* d_out, int out_size, void* d_ws, size_t ws_size,
                              hipStream_t stream)
{
    (void)in_sizes; (void)n_in; (void)out_size; (void)ws_size;
    const float* q     = (const float*)d_in[0];
    const float* k     = (const float*)d_in[1];
    const float* mask  = (const float*)d_in[2];
    const float* wq    = (const float*)d_in[3];
    const float* wk    = (const float*)d_in[4];
    const float* wv    = (const float*)d_in[5];
    const float* wo    = (const float*)d_in[6];
    const float* w1    = (const float*)d_in[7];
    const float* b1    = (const float*)d_in[8];
    const float* w2    = (const float*)d_in[9];
    const float* b2    = (const float*)d_in[10];
    const float* g1    = (const float*)d_in[11];
    const float* beta1 = (const float*)d_in[12];
    const float* g2    = (const float*)d_in[13];
    const float* beta2 = (const float*)d_in[14];
    float* out = (float*)d_out;

    // workspace layout (51 MB total)
    uint8_t* base = (uint8_t*)d_ws;
    ushort* qpb = (ushort*)(base);                        // 8 MB: Q-proj, then ctx
    ushort* kpb = (ushort*)(base + (8u  << 20));          // 8 MB: K-proj, then FFN h
    ushort* vpb = (ushort*)(base + (16u << 20));          // 8 MB: V-proj
    float*  ao  = (float*) (base + (24u << 20));          // 16 MB: attn_out -> out1 (in place)
    ushort* o1b = (ushort*)(base + (40u << 20));          // 8 MB: out1 bf16 copy
    ushort* wt  = (ushort*)(base + (48u << 20));          // 3 MB: 6x WT bf16
    ushort* wtq = wt;
    ushort* wtk = wt + 1u * DD * DD;
    ushort* wtv = wt + 2u * DD * DD;
    ushort* wto = wt + 3u * DD * DD;
    ushort* wt1 = wt + 4u * DD * DD;
    ushort* wt2 = wt + 5u * DD * DD;

    const dim3 blk(256);
    const dim3 ggrid(DD / 128, NROWS / 128);     // 4 x 64 = 256 blocks

    // 0) weight transposes (bf16 WT[n][k])
    wtrans_kernel<<<dim3(8, 8, 6), blk, 0, stream>>>(wq, wk, wv, wo, w1, w2, wt);

    // 1) projections: fp32 A -> bf16 C
    gemm2_kernel<float, ushort, 0><<<ggrid, blk, 0, stream>>>(q, wtq, nullptr, qpb);
    gemm2_kernel<float, ushort, 0><<<ggrid, blk, 0, stream>>>(k, wtk, nullptr, kpb);
    gemm2_kernel<float, ushort, 0><<<ggrid, blk, 0, stream>>>(k, wtv, nullptr, vpb);

    // 2) attention (bf16 in/out; ctx in-place into qpb)
    attn_mfma_kernel<<<dim3(SS / 64, HH, BB), blk, 0, stream>>>(qpb, kpb, vpb, mask, qpb);

    // 3) attn_out = ctx @ wo (fp32); out1 = LN1(q + attn_out) in-place + bf16 copy
    gemm2_kernel<ushort, float, 0><<<ggrid, blk, 0, stream>>>(qpb, wto, nullptr, ao);
    ln_kernel<<<dim3(NROWS), blk, 0, stream>>>(ao, q, g1, beta1, ao, o1b);

    // 4) FFN: h = leaky(out1 @ w1 + b1) bf16; ffn_out = h @ w2 + b2 fp32 -> out
    gemm2_kernel<ushort, ushort, 1><<<ggrid, blk, 0, stream>>>(o1b, wt1, b1, kpb);
    gemm2_kernel<ushort, float, 0><<<ggrid, blk, 0, stream>>>(kpb, wt2, b2, out);

    // 5) out = LN2(out1 + ffn_out)
    ln_kernel<<<dim3(NROWS), blk, 0, stream>>>(out, ao, g2, beta2, out, nullptr);
}

// Round 9
// 338.433 us; speedup vs baseline: 3.5961x; 1.1494x over previous
//
#include <hip/hip_runtime.h>
#include <hip/hip_bf16.h>
#include <math.h>

#define BB 4
#define SS 2048
#define DD 512
#define HH 8
#define DEPTH 64
#define NROWS (BB*SS)
#define LN_EPS 1e-6f

typedef __attribute__((ext_vector_type(8))) short bf16x8;
typedef __attribute__((ext_vector_type(4))) float f32x4;

static __device__ inline ushort f2bf(float f) {
    __hip_bfloat16 h = __float2bfloat16(f);
    return *reinterpret_cast<ushort*>(&h);
}

// ---------------------------------------------------------------------------
// Weight pre-transpose: W[512][512] fp32 -> WT[n][k] bf16, all 6 weights.
// ---------------------------------------------------------------------------
__global__ __launch_bounds__(256) void wtrans_kernel(
    const float* __restrict__ w0, const float* __restrict__ w1,
    const float* __restrict__ w2, const float* __restrict__ w3,
    const float* __restrict__ w4, const float* __restrict__ w5,
    ushort* __restrict__ wt)
{
    const float* W;
    switch (blockIdx.z) {
        case 0: W = w0; break; case 1: W = w1; break; case 2: W = w2; break;
        case 3: W = w3; break; case 4: W = w4; break; default: W = w5; break;
    }
    ushort* WT = wt + (size_t)blockIdx.z * DD * DD;

    __shared__ ushort t[64][72];
    const int kt = blockIdx.x * 64, nt = blockIdx.y * 64;
    const int tid = threadIdx.x;
    const int r = tid >> 2, cg = tid & 3;

    #pragma unroll
    for (int q = 0; q < 4; ++q) {
        float4 v = *reinterpret_cast<const float4*>(
            &W[(size_t)(kt + r) * DD + nt + cg * 16 + q * 4]);
        t[r][cg * 16 + q * 4 + 0] = f2bf(v.x);
        t[r][cg * 16 + q * 4 + 1] = f2bf(v.y);
        t[r][cg * 16 + q * 4 + 2] = f2bf(v.z);
        t[r][cg * 16 + q * 4 + 3] = f2bf(v.w);
    }
    __syncthreads();

    ushort tmp[16];
    #pragma unroll
    for (int i = 0; i < 16; ++i) tmp[i] = t[cg * 16 + i][r];
    *reinterpret_cast<bf16x8*>(&WT[(size_t)(nt + r) * DD + kt + cg * 16]) =
        *reinterpret_cast<bf16x8*>(&tmp[0]);
    *reinterpret_cast<bf16x8*>(&WT[(size_t)(nt + r) * DD + kt + cg * 16 + 8]) =
        *reinterpret_cast<bf16x8*>(&tmp[8]);
}

// ---------------------------------------------------------------------------
// bf16-MFMA GEMM core, retiled for occupancy: BM=64, BN=128, BK=32,
// 256 threads (4 waves, 2x2), wave owns 32x64 (2x4 fragments).
// Grid (DD/128, NROWS/64) = 512 blocks = 2 blocks/CU (was 256 = 1/CU).
// Same LDS layout / fragment / C-D conventions as the verified kernel;
// K-summation order per output element identical -> bit-identical numerics.
// ---------------------------------------------------------------------------
#define LDP 40   // LDS row pitch in ushorts (80 B)

template<typename AT, typename CT, int ACT>
static __device__ __forceinline__ void gemm3_body(
    const AT* __restrict__ A, const ushort* __restrict__ WT,
    const float* __restrict__ bias, CT* __restrict__ C,
    ushort* As, ushort* Bs, int bm, int bn)
{
    const int tid  = threadIdx.x;
    const int wave = tid >> 6;
    const int lane = tid & 63;
    const int wr = wave >> 1, wc = wave & 1;   // 2x2 waves: 32-row x 64-col
    const int lm = lane & 15;
    const int kg = lane >> 4;

    f32x4 acc[2][4] = {};

    const int ar = tid >> 2;            // A row 0..63
    const int ac = (tid & 3) * 8;       // A col 0,8,16,24
    const int br = tid >> 1;            // B row (C col) 0..127
    const int bh = tid & 1;             // B k-half

    for (int k0 = 0; k0 < DD; k0 += 32) {
        // --- stage A tile: 64 rows x 32 k (8 elems/thread) ---
        if constexpr (sizeof(AT) == 4) {
            const float* ga = (const float*)&A[(size_t)(bm + ar) * DD + k0 + ac];
            float4 v0 = *reinterpret_cast<const float4*>(ga);
            float4 v1 = *reinterpret_cast<const float4*>(ga + 4);
            ushort tmp[8];
            tmp[0] = f2bf(v0.x); tmp[1] = f2bf(v0.y);
            tmp[2] = f2bf(v0.z); tmp[3] = f2bf(v0.w);
            tmp[4] = f2bf(v1.x); tmp[5] = f2bf(v1.y);
            tmp[6] = f2bf(v1.z); tmp[7] = f2bf(v1.w);
            *reinterpret_cast<bf16x8*>(&As[ar * LDP + ac]) =
                *reinterpret_cast<bf16x8*>(tmp);
        } else {
            const ushort* ga = (const ushort*)&A[(size_t)(bm + ar) * DD + k0 + ac];
            *reinterpret_cast<bf16x8*>(&As[ar * LDP + ac]) =
                *reinterpret_cast<const bf16x8*>(ga);
        }
        // --- stage B tile: Bs[col][k] <- WT[bn+col][k0..+31] (16 elems/thread)
        {
            const ushort* gw = &WT[(size_t)(bn + br) * DD + k0 + bh * 16];
            *reinterpret_cast<bf16x8*>(&Bs[br * LDP + bh * 16]) =
                *reinterpret_cast<const bf16x8*>(gw);
            *reinterpret_cast<bf16x8*>(&Bs[br * LDP + bh * 16 + 8]) =
                *reinterpret_cast<const bf16x8*>(gw + 8);
        }
        __syncthreads();

        bf16x8 af[2], bfr[4];
        #pragma unroll
        for (int m = 0; m < 2; ++m)
            af[m] = *reinterpret_cast<const bf16x8*>(
                &As[(wr * 32 + m * 16 + lm) * LDP + kg * 8]);
        #pragma unroll
        for (int n = 0; n < 4; ++n)
            bfr[n] = *reinterpret_cast<const bf16x8*>(
                &Bs[(wc * 64 + n * 16 + lm) * LDP + kg * 8]);
        #pragma unroll
        for (int m = 0; m < 2; ++m)
            #pragma unroll
            for (int n = 0; n < 4; ++n)
                acc[m][n] = __builtin_amdgcn_mfma_f32_16x16x32_bf16(
                    af[m], bfr[n], acc[m][n], 0, 0, 0);
        __syncthreads();
    }

    // --- epilogue: C/D layout col=lane&15, row=(lane>>4)*4+reg (verified) ---
    #pragma unroll
    for (int m = 0; m < 2; ++m) {
        #pragma unroll
        for (int n = 0; n < 4; ++n) {
            const int col = bn + wc * 64 + n * 16 + lm;
            const float bv = bias ? bias[col] : 0.f;
            #pragma unroll
            for (int j = 0; j < 4; ++j) {
                const int row = bm + wr * 32 + m * 16 + kg * 4 + j;
                float v = acc[m][n][j] + bv;
                if (ACT == 1) v = (v > 0.f) ? v : 0.2f * v;
                if constexpr (sizeof(CT) == 4)
                    C[(size_t)row * DD + col] = v;
                else
                    C[(size_t)row * DD + col] = f2bf(v);
            }
        }
    }
}

template<typename AT, typename CT, int ACT>
__global__ __launch_bounds__(256) void gemm3_kernel(
    const AT* __restrict__ A, const ushort* __restrict__ WT,
    const float* __restrict__ bias, CT* __restrict__ C)
{
    __shared__ __align__(16) ushort As[64 * LDP];
    __shared__ __align__(16) ushort Bs[128 * LDP];
    gemm3_body<AT, CT, ACT>(A, WT, bias, C, As, Bs,
                            blockIdx.y * 64, blockIdx.x * 128);
}

// Fused Q/K/V projections: grid.z selects (input, weight, output).
__global__ __launch_bounds__(256) void gemm3_proj_kernel(
    const float* __restrict__ q, const float* __restrict__ k,
    const ushort* __restrict__ wt, ushort* __restrict__ outb)
{
    __shared__ __align__(16) ushort As[64 * LDP];
    __shared__ __align__(16) ushort Bs[128 * LDP];
    const int z = blockIdx.z;
    const float* A = (z == 0) ? q : k;
    const ushort* WT = wt + (size_t)z * DD * DD;
    ushort* C = outb + (size_t)z * NROWS * DD;
    gemm3_body<float, ushort, 0>(A, WT, nullptr, C, As, Bs,
                                 blockIdx.y * 64, blockIdx.x * 128);
}

// ---------------------------------------------------------------------------
// bf16-MFMA flash attention (unchanged from passing round 8)
// ---------------------------------------------------------------------------
#define AP 72
#define SP 68

__global__ __launch_bounds__(256) void attn_mfma_kernel(
    const ushort* __restrict__ qp, const ushort* __restrict__ kp,
    const ushort* __restrict__ vp, const float* __restrict__ mask,
    ushort* __restrict__ ctx)
{
    __shared__ __align__(16) ushort qs[64 * AP];
    __shared__ __align__(16) ushort ksh[64 * AP];
    __shared__ __align__(16) ushort vsT[64 * AP];
    __shared__ __align__(16) ushort pt[64 * AP];
    __shared__ __align__(16) float  st[64 * SP];
    __shared__ float crow[64];
    __shared__ float linv[64];

    const int qt = blockIdx.x, h = blockIdx.y, b = blockIdx.z;
    const int tid = threadIdx.x;
    const int wave = tid >> 6, lane = tid & 63;
    const int lm = lane & 15, kg = lane >> 4;
    const int r4 = tid >> 2;
    const int c4 = tid & 3;

    {
        const ushort* gq = &qp[(size_t)(b*SS + qt*64 + r4)*DD + h*DEPTH + c4*16];
        *reinterpret_cast<bf16x8*>(&qs[r4*AP + c4*16])     = *reinterpret_cast<const bf16x8*>(gq);
        *reinterpret_cast<bf16x8*>(&qs[r4*AP + c4*16 + 8]) = *reinterpret_cast<const bf16x8*>(gq + 8);
    }

    f32x4 acc[4] = {};
    float m_i = -1e30f, l_i = 0.f;

    for (int kt = 0; kt < SS/64; ++kt) {
        __syncthreads();

        {
            const size_t gb = (size_t)(b*SS + kt*64 + r4)*DD + h*DEPTH + c4*16;
            *reinterpret_cast<bf16x8*>(&ksh[r4*AP + c4*16])     = *reinterpret_cast<const bf16x8*>(&kp[gb]);
            *reinterpret_cast<bf16x8*>(&ksh[r4*AP + c4*16 + 8]) = *reinterpret_cast<const bf16x8*>(&kp[gb + 8]);

            ushort tv[16];
            *reinterpret_cast<bf16x8*>(&tv[0]) = *reinterpret_cast<const bf16x8*>(&vp[gb]);
            *reinterpret_cast<bf16x8*>(&tv[8]) = *reinterpret_cast<const bf16x8*>(&vp[gb + 8]);
            #pragma unroll
            for (int i = 0; i < 16; ++i) {
                const int dloc = c4*16 + i;
                const int e = (((r4>>3) ^ ((dloc>>3)&7)) << 3) | (r4 & 7);
                vsT[dloc*AP + e] = tv[i];
            }
        }
        __syncthreads();

        {
            f32x4 s[4] = {};
            #pragma unroll
            for (int ks_ = 0; ks_ < 2; ++ks_) {
                bf16x8 bfrag = *reinterpret_cast<const bf16x8*>(
                    &ksh[(wave*16 + lm)*AP + ks_*32 + kg*8]);
                #pragma unroll
                for (int m = 0; m < 4; ++m) {
                    bf16x8 afrag = *reinterpret_cast<const bf16x8*>(
                        &qs[(m*16 + lm)*AP + ks_*32 + kg*8]);
                    s[m] = __builtin_amdgcn_mfma_f32_16x16x32_bf16(
                        afrag, bfrag, s[m], 0, 0, 0);
                }
            }
            const int kcol = kt*64 + wave*16 + lm;
            const float mval = mask[b*SS + kcol] * (-1e9f);
            #pragma unroll
            for (int m = 0; m < 4; ++m)
                #pragma unroll
                for (int j = 0; j < 4; ++j)
                    st[(m*16 + kg*4 + j)*SP + wave*16 + lm] = s[m][j]*0.125f + mval;
        }
        __syncthreads();

        {
            float p[16];
            #pragma unroll
            for (int q = 0; q < 4; ++q) {
                float4 t = *reinterpret_cast<const float4*>(&st[r4*SP + c4*16 + q*4]);
                p[q*4+0] = t.x; p[q*4+1] = t.y; p[q*4+2] = t.z; p[q*4+3] = t.w;
            }
            float mt = p[0];
            #pragma unroll
            for (int i = 1; i < 16; ++i) mt = fmaxf(mt, p[i]);
            mt = fmaxf(mt, __shfl_xor(mt, 1));
            mt = fmaxf(mt, __shfl_xor(mt, 2));
            const float mnew = fmaxf(m_i, mt);
            const float corr = __expf(m_i - mnew);
            float sum = 0.f;
            ushort tmp[16];
            #pragma unroll
            for (int i = 0; i < 16; ++i) {
                float e = __expf(p[i] - mnew);
                sum += e;
                tmp[i] = f2bf(e);
            }
            sum += __shfl_xor(sum, 1);
            sum += __shfl_xor(sum, 2);
            l_i = l_i * corr + sum;
            m_i = mnew;
            *reinterpret_cast<bf16x8*>(&pt[r4*AP + c4*16])     = *reinterpret_cast<bf16x8*>(&tmp[0]);
            *reinterpret_cast<bf16x8*>(&pt[r4*AP + c4*16 + 8]) = *reinterpret_cast<bf16x8*>(&tmp[8]);
            if (c4 == 0) crow[r4] = corr;
        }
        __syncthreads();

        {
            #pragma unroll
            for (int m = 0; m < 4; ++m)
                #pragma unroll
                for (int j = 0; j < 4; ++j)
                    acc[m][j] *= crow[m*16 + kg*4 + j];

            const int dloc = wave*16 + lm;
            const int zz = (dloc >> 3) & 7;
            #pragma unroll
            for (int ks_ = 0; ks_ < 2; ++ks_) {
                const int chunk = (ks_*4 + kg) ^ zz;
                bf16x8 bfrag = *reinterpret_cast<const bf16x8*>(
                    &vsT[dloc*AP + chunk*8]);
                #pragma unroll
                for (int m = 0; m < 4; ++m) {
                    bf16x8 afrag = *reinterpret_cast<const bf16x8*>(
                        &pt[(m*16 + lm)*AP + ks_*32 + kg*8]);
                    acc[m] = __builtin_amdgcn_mfma_f32_16x16x32_bf16(
                        afrag, bfrag, acc[m], 0, 0, 0);
                }
            }
        }
    }

    if (c4 == 0) linv[r4] = 1.f / l_i;
    __syncthreads();

    {
        const int dloc = wave*16 + lm;
        #pragma unroll
        for (int m = 0; m < 4; ++m)
            #pragma unroll
            for (int j = 0; j < 4; ++j) {
                const int row = m*16 + kg*4 + j;
                ctx[(size_t)(b*SS + qt*64 + row)*DD + h*DEPTH + dloc] =
                    f2bf(acc[m][j] * linv[row]);
            }
    }
}

// ---------------------------------------------------------------------------
// LayerNorm with residual (unchanged)
// ---------------------------------------------------------------------------
__global__ __launch_bounds__(256) void ln_kernel(
    const float* __restrict__ x, const float* __restrict__ res,
    const float* __restrict__ g, const float* __restrict__ bta,
    float* __restrict__ out, ushort* __restrict__ outb)
{
    const int row = blockIdx.x;
    const int tid = threadIdx.x;
    const size_t base = (size_t)row * DD + tid * 2;

    float2 xv = *reinterpret_cast<const float2*>(&x[base]);
    float2 rv = *reinterpret_cast<const float2*>(&res[base]);
    float v0 = xv.x + rv.x, v1 = xv.y + rv.y;

    float s = v0 + v1;
    float ss = v0 * v0 + v1 * v1;
    #pragma unroll
    for (int off = 32; off > 0; off >>= 1) {
        s  += __shfl_down(s, off);
        ss += __shfl_down(ss, off);
    }
    __shared__ float red[2][4];
    const int wid = tid >> 6, lane = tid & 63;
    if (lane == 0) { red[0][wid] = s; red[1][wid] = ss; }
    __syncthreads();
    const float tot = red[0][0] + red[0][1] + red[0][2] + red[0][3];
    const float tsq = red[1][0] + red[1][1] + red[1][2] + red[1][3];
    const float mu = tot * (1.f / DD);
    const float var = tsq * (1.f / DD) - mu * mu;
    const float rs = rsqrtf(var + LN_EPS);

    float2 gv = *reinterpret_cast<const float2*>(&g[tid * 2]);
    float2 bv = *reinterpret_cast<const float2*>(&bta[tid * 2]);
    float2 ov;
    ov.x = (v0 - mu) * rs * gv.x + bv.x;
    ov.y = (v1 - mu) * rs * gv.y + bv.y;
    *reinterpret_cast<float2*>(&out[base]) = ov;
    if (outb) {
        ushort2 ob; ob.x = f2bf(ov.x); ob.y = f2bf(ov.y);
        *reinterpret_cast<ushort2*>(&outb[base]) = ob;
    }
}

// ---------------------------------------------------------------------------
extern "C" void kernel_launch(void* const* d_in, const int* in_sizes, int n_in,
                              void* d_out, int out_size, void* d_ws, size_t ws_size,
                              hipStream_t stream)
{
    (void)in_sizes; (void)n_in; (void)out_size; (void)ws_size;
    const float* q     = (const float*)d_in[0];
    const float* k     = (const float*)d_in[1];
    const float* mask  = (const float*)d_in[2];
    const float* wq    = (const float*)d_in[3];
    const float* wk    = (const float*)d_in[4];
    const float* wv    = (const float*)d_in[5];
    const float* wo    = (const float*)d_in[6];
    const float* w1    = (const float*)d_in[7];
    const float* b1    = (const float*)d_in[8];
    const float* w2    = (const float*)d_in[9];
    const float* b2    = (const float*)d_in[10];
    const float* g1    = (const float*)d_in[11];
    const float* beta1 = (const float*)d_in[12];
    const float* g2    = (const float*)d_in[13];
    const float* beta2 = (const float*)d_in[14];
    float* out = (float*)d_out;

    // workspace layout (51 MB total)
    uint8_t* base = (uint8_t*)d_ws;
    ushort* qpb = (ushort*)(base);                        // 8 MB: Q-proj, then ctx
    ushort* kpb = (ushort*)(base + (8u  << 20));          // 8 MB: K-proj, then FFN h
    ushort* vpb = (ushort*)(base + (16u << 20));          // 8 MB: V-proj
    float*  ao  = (float*) (base + (24u << 20));          // 16 MB: attn_out -> out1
    ushort* o1b = (ushort*)(base + (40u << 20));          // 8 MB: out1 bf16 copy
    ushort* wt  = (ushort*)(base + (48u << 20));          // 3 MB: 6x WT bf16
    ushort* wto = wt + 3u * DD * DD;
    ushort* wt1 = wt + 4u * DD * DD;
    ushort* wt2 = wt + 5u * DD * DD;

    const dim3 blk(256);
    const dim3 ggrid(DD / 128, NROWS / 64);      // 4 x 128 = 512 blocks

    // 0) weight transposes (bf16 WT[n][k])
    wtrans_kernel<<<dim3(8, 8, 6), blk, 0, stream>>>(wq, wk, wv, wo, w1, w2, wt);

    // 1) fused Q/K/V projections (grid.z = 3 -> 1536 blocks resident)
    gemm3_proj_kernel<<<dim3(DD / 128, NROWS / 64, 3), blk, 0, stream>>>(q, k, wt, qpb);

    // 2) attention (bf16 in/out; ctx in-place into qpb)
    attn_mfma_kernel<<<dim3(SS / 64, HH, BB), blk, 0, stream>>>(qpb, kpb, vpb, mask, qpb);

    // 3) attn_out = ctx @ wo (fp32); out1 = LN1(q + attn_out) in-place + bf16 copy
    gemm3_kernel<ushort, float, 0><<<ggrid, blk, 0, stream>>>(qpb, wto, nullptr, ao);
    ln_kernel<<<dim3(NROWS), blk, 0, stream>>>(ao, q, g1, beta1, ao, o1b);

    // 4) FFN: h = leaky(out1 @ w1 + b1) bf16; ffn_out = h @ w2 + b2 fp32 -> out
    gemm3_kernel<ushort, ushort, 1><<<ggrid, blk, 0, stream>>>(o1b, wt1, b1, kpb);
    gemm3_kernel<ushort, float, 0><<<ggrid, blk, 0, stream>>>(kpb, wt2, b2, out);

    // 5) out = LN2(out1 + ffn_out)
    ln_kernel<<<dim3(NROWS), blk, 0, stream>>>(out, ao, g2, beta2, out, nullptr);
}